// Round 10
// baseline (137.167 us; speedup 1.0000x reference)
//
#include <hip/hip_runtime.h>
#include <hip/hip_bf16.h>

// SegmentDeactivation: KAN layer folded into one bf16 GEMM.
// K = 512*36 (dense-ified 4-sparse cubic B-spline bases) + 512 (silu(x)·W_base)
//   + 512 (x·masked-slope) = 19456. bias = sum of masked intercepts.
// R20: R18 (best, 132.8us) + depth-2 prefetch. Same 256x128/BK64/512thr
//      geometry, counted-vmcnt discipline, SPLITS=16 (KPS=1216=19*64,
//      grid 256 = 1 blk/CU). LDS now TRIPLE-buffered (3x48KB = 144KB):
//      STAGE(t+2) issued in epoch t, in-loop wait vmcnt(12) (= 2 stages
//      in flight, STAGE(t) landed) -> loads get ~2 MFMA epochs (~600cy)
//      to cover HBM/LLC latency (R19 showed 1 epoch at 64KB/stage does
//      not cover it). Epilogue drains 12 -> 6 -> 0. Barrier scheme and
//      numerics identical to R18 (buffer staged in epoch t last read in
//      t-3, sealed by two barriers).

typedef unsigned short u16;
typedef unsigned int u32;
typedef unsigned long long u64;
typedef __attribute__((ext_vector_type(8))) short short8;
typedef __attribute__((ext_vector_type(4))) float floatx4;

#define IN_F 512
#define OUT_F 512
#define BATCH 1024
#define K_SPLINE (IN_F * 36)            // 18432
#define K_BASE_OFF K_SPLINE
#define K_LIN_OFF (K_SPLINE + IN_F)
#define K_TOT (K_SPLINE + 2 * IN_F)     // 19456
#define SPLITS 16                       // uniform: 16 x 1216 (= 19*64)
#define KPS 1216
#define NIT 19
#define MN (BATCH * OUT_F)

static __device__ inline u16 f2b(float f) {
  union { float f; u32 u; } v; v.f = f;
  u32 r = v.u + 0x7FFFu + ((v.u >> 16) & 1u);  // round-nearest-even
  return (u16)(r >> 16);
}
static __device__ inline float b2f(u32 lo16) {  // bf16 bits (low 16) -> float
  union { u32 u; float f; } v; v.u = lo16 << 16; return v.f;
}

// ---- prep (fused): blocks 0..1023 = pack_b (one o-half each, per-block mask
//      detect, bias block-reduce); blocks 1024..3071 = dense-A build
//      (bix = blk-1024 = b*2 + half; thread t owns (b, i = i0+t)).
__global__ __launch_bounds__(256) void prep_kernel(
    const float* __restrict__ bw, const float* __restrict__ sw,
    const float* __restrict__ sc, const void* __restrict__ maskp,
    const float* __restrict__ x, u16* __restrict__ B,
    float* __restrict__ bias_part, u16* __restrict__ A) {
  __shared__ __align__(16) u64 lds64[1120 * 4];  // 35840B
  __shared__ int sflag;
  __shared__ float ws4[4];
  int blk = blockIdx.x, t = threadIdx.x;

  if (blk >= 1024) {
    // ---- dense A build
    int bix = blk - 1024;
    int b = bix >> 1;
    int i0 = (bix & 1) << 8;
    int i = i0 + t;
    float xv = x[(size_t)b * IN_F + i];

    // zero own 36-col row (72B = 9 u64), no barrier needed before scatter
    u64* myrow = lds64 + t * 9;
#pragma unroll
    for (int j = 0; j < 9; ++j) myrow[j] = 0;

    int mc = (int)floorf((xv + 1.1875f) * 16.0f);
    float gm = (float)mc * 0.0625f - 1.1875f;
    if (xv < gm) { mc -= 1; gm -= 0.0625f; }
    else if (xv >= gm + 0.0625f) { mc += 1; gm += 0.0625f; }
    if (mc >= 0 && mc <= 37) {
      float t_ = (xv - gm) * 16.0f;
      float t2 = t_ * t_, t3 = t2 * t_;
      float omt = 1.0f - t_;
      u16 r0 = f2b(omt * omt * omt * (1.0f / 6.0f));
      u16 r1 = f2b((3.0f * t3 - 6.0f * t2 + 4.0f) * (1.0f / 6.0f));
      u16 r2 = f2b((-3.0f * t3 + 3.0f * t2 + 3.0f * t_ + 1.0f) * (1.0f / 6.0f));
      float f0 = b2f(r0), f1 = b2f(r1), f2 = b2f(r2);
      u16 bv[4] = {r0, r1, r2, f2b(1.0f - f0 - f1 - f2)};
      u16* lds_u = (u16*)lds64;
#pragma unroll
      for (int j = 0; j < 4; ++j) {
        int c = mc - 3 + j;
        if ((u32)c < 35u) lds_u[t * 36 + c] = bv[j];
      }
    }
    __syncthreads();

    // coalesced dump: 256 rows x 36 u16 = 2304 u64
    u64* dstA = (u64*)(A + (size_t)b * K_TOT + (size_t)i0 * 36);
#pragma unroll
    for (int j = 0; j < 9; ++j) dstA[j * 256 + t] = lds64[j * 256 + t];

    // base / linear columns of A
    float sl = xv / (1.0f + __expf(-xv));
    A[(size_t)b * K_TOT + K_BASE_OFF + i] = f2b(sl);
    A[(size_t)b * K_TOT + K_LIN_OFF + i] = f2b(xv);
    return;
  }

  // ---- pack_b: id = o*512+i, o = blk>>1
  float* lds_f = (float*)lds64;
  int id = blk * 256 + t;
  int o = id >> 9, i = id & 511;
  int i0 = (blk & 1) * 256;

  // stage 35*256 floats = 2240 float4, vectorized (G13)
  const float* swb = sw + ((size_t)o * 512 + i0) * 35;
  const floatx4* sw4 = (const floatx4*)swb;
  floatx4* lds4 = (floatx4*)lds_f;
#pragma unroll
  for (int j = 0; j < 8; ++j) lds4[j * 256 + t] = sw4[j * 256 + t];
  if (t < 192) lds4[8 * 256 + t] = sw4[8 * 256 + t];

  // per-block mask dtype detect over THIS block's entries only.
  const u32* mw = (const u32*)maskp;
  if (t == 0) sflag = 0;
  __syncthreads();
  if (t < 64) {
    u32 w2 = mw[blk * 64 + t];   // uint8 window: bytes [blk*256,+256)
    if ((w2 & 0xFFFFFF00u) && w2 != 0x3F800000u) atomicOr(&sflag, 1);
  }
  __syncthreads();
  int fl = sflag;
  if (!(fl & 1)) {
    u32 w1 = mw[blk * 256 + t];  // int32/f32 window: words [blk*256,+256)
    if (w1 == 0x3F800000u) atomicOr(&sflag, 2);
  }
  __syncthreads();
  fl = sflag;
  bool mk;
  if (fl & 1)      mk = ((const unsigned char*)maskp)[id] != 0;
  else if (fl & 2) mk = ((const float*)maskp)[id] != 0.0f;
  else             mk = ((const int*)maskp)[id] != 0;

  float s = sc[id];
  float w[35];
#pragma unroll
  for (int c = 0; c < 35; ++c) w[c] = lds_f[t * 35 + c] * s;
  __syncthreads();

  // linear fallback params from endpoint spline values (dx = 2 exactly)
  float ys = (w[0] + 4.0f * w[1] + w[2]) * (1.0f / 6.0f);
  float ye = (w[32] + 4.0f * w[33] + w[34]) * (1.0f / 6.0f);
  float a = (ye - ys) * 0.5f;
  float bl = ys + a;

  // build out-row in regs (static indexing), store as 9 u64
  union { u16 r16[36]; u64 r64[9]; } ur;
#pragma unroll
  for (int c = 0; c < 35; ++c) ur.r16[c] = f2b(mk ? 0.0f : w[c]);
  ur.r16[35] = 0;
  u64* myrow = lds64 + t * 9;
#pragma unroll
  for (int j = 0; j < 9; ++j) myrow[j] = ur.r64[j];

  B[(size_t)o * K_TOT + K_BASE_OFF + i] = f2b(bw[id]);
  B[(size_t)o * K_TOT + K_LIN_OFF + i] = f2b(mk ? a : 0.0f);

  // bias block-reduce: sum of (mk ? bl : 0) over this block's 256 i's
  float v = mk ? bl : 0.0f;
#pragma unroll
  for (int off = 32; off >= 1; off >>= 1) v += __shfl_down(v, off);
  if ((t & 63) == 0) ws4[t >> 6] = v;
  __syncthreads();
  if (t == 0) bias_part[blk] = ws4[0] + ws4[1] + ws4[2] + ws4[3];

  u64* dst = (u64*)(B + (size_t)o * K_TOT + (size_t)i0 * 36);
#pragma unroll
  for (int j = 0; j < 9; ++j) dst[j * 256 + t] = lds64[j * 256 + t];
}

// ---- pipelined GEMM: 256x128 tile, BK=64, 512 thr (8 waves 4Mx2N, wave =
// 64x64, acc 4x4, 32 MFMA/epoch). Grid 256 = 1 blk/CU.
// TRIPLE-buffered LDS (144KB), depth-2 prefetch. Epoch t:
//   STAGE(t+2) -> buf[(t+2)%3] (6 gload_lds w16)
//   s_waitcnt vmcnt(12)   [STAGE(t) landed; t+1, t+2 in flight]
//   s_barrier; 32 MFMA on buf[t%3]; s_barrier.
// Epilogue drains vmcnt 6 -> 0.
__global__ __launch_bounds__(512, 2) void gemm_fused(const u16* __restrict__ A,
                                                     const u16* __restrict__ Bp,
                                                     u16* __restrict__ P) {
  __shared__ u16 As[3][256 * 64];   // 3 x 32 KB
  __shared__ u16 Bs[3][128 * 64];   // 3 x 16 KB

  int t = threadIdx.x;
  int p = blockIdx.x;
  int tile = p & 15, ks = p >> 4;        // 16 tiles x 16 splits
  int bm = tile >> 2, bn = tile & 3;

  int w = t >> 6, l = t & 63;
  int wm = w & 3, wn = w >> 2;           // 4 M-waves x 2 N-waves

  floatx4 acc[4][4];
#pragma unroll
  for (int pp = 0; pp < 4; ++pp)
#pragma unroll
    for (int q = 0; q < 4; ++q) acc[pp][q] = (floatx4)0.0f;

  int k0s = ks * KPS;

  // staging: thread t covers (row ra = t>>3 in each 64-row group, chunk t&7);
  // global source column pre-swizzled so linear LDS dest == swizzled layout.
  int ra = t >> 3;                       // 0..63
  int cg = (t & 7) ^ (ra & 7);
  const u16* Agp = A + (size_t)(bm * 256 + ra) * K_TOT + k0s + cg * 8;
  const u16* Bgp = Bp + (size_t)(bn * 128 + ra) * K_TOT + k0s + cg * 8;

  int mr = l & 15;
  int cq = l >> 4;

  // 6 gload_lds w16 per thread per STAGE (4 A-groups + 2 B-groups)
#define STAGE(buf, koff)                                                       \
  do {                                                                         \
    const u16* a_ = Agp + (koff);                                              \
    const u16* b_ = Bgp + (koff);                                              \
    u16* asb = &As[buf][0];                                                    \
    u16* bsb = &Bs[buf][0];                                                    \
    __builtin_amdgcn_global_load_lds(                                          \
        (const __attribute__((address_space(1))) void*)a_,                     \
        (__attribute__((address_space(3))) void*)(asb + t * 8), 16, 0, 0);     \
    __builtin_amdgcn_global_load_lds(                                          \
        (const __attribute__((address_space(1))) void*)(a_ + (size_t)64 * K_TOT),   \
        (__attribute__((address_space(3))) void*)(asb + 4096 + t * 8), 16, 0, 0);   \
    __builtin_amdgcn_global_load_lds(                                          \
        (const __attribute__((address_space(1))) void*)(a_ + (size_t)128 * K_TOT),  \
        (__attribute__((address_space(3))) void*)(asb + 8192 + t * 8), 16, 0, 0);   \
    __builtin_amdgcn_global_load_lds(                                          \
        (const __attribute__((address_space(1))) void*)(a_ + (size_t)192 * K_TOT),  \
        (__attribute__((address_space(3))) void*)(asb + 12288 + t * 8), 16, 0, 0);  \
    __builtin_amdgcn_global_load_lds(                                          \
        (const __attribute__((address_space(1))) void*)b_,                     \
        (__attribute__((address_space(3))) void*)(bsb + t * 8), 16, 0, 0);     \
    __builtin_amdgcn_global_load_lds(                                          \
        (const __attribute__((address_space(1))) void*)(b_ + (size_t)64 * K_TOT),   \
        (__attribute__((address_space(3))) void*)(bsb + 4096 + t * 8), 16, 0, 0);   \
  } while (0)

  // prologue: tiles 0 and 1 in flight
  STAGE(0, 0);
  STAGE(1, 64);

  int cur = 0;
  for (int kk = 0; kk < NIT; ++kk) {
    if (kk + 2 < NIT) {
      int nb = (cur >= 1) ? (cur - 1) : (cur + 2);   // (cur+2)%3
      STAGE(nb, (kk + 2) * 64);          // flies across 2 epochs
      asm volatile("s_waitcnt vmcnt(12)" ::: "memory");  // STAGE(kk) landed
    } else if (kk + 2 == NIT) {
      asm volatile("s_waitcnt vmcnt(6)" ::: "memory");   // STAGE(NIT-2) landed
    } else {
      asm volatile("s_waitcnt vmcnt(0)" ::: "memory");   // last tile landed
    }
    __builtin_amdgcn_s_barrier();        // all waves' cur-stage complete
    __builtin_amdgcn_sched_barrier(0);

    const u16* Ac = &As[cur][0];
    const u16* Bc = &Bs[cur][0];
#pragma unroll
    for (int h = 0; h < 2; ++h) {
      short8 af[4], bf[4];
      int c = h * 4 + cq;
#pragma unroll
      for (int tm = 0; tm < 4; ++tm) {
        int row = wm * 64 + tm * 16 + mr;
        af[tm] = *(const short8*)&Ac[row * 64 + ((c ^ (row & 7)) << 3)];
      }
#pragma unroll
      for (int tn = 0; tn < 4; ++tn) {
        int row = wn * 64 + tn * 16 + mr;
        bf[tn] = *(const short8*)&Bc[row * 64 + ((c ^ (row & 7)) << 3)];
      }
#pragma unroll
      for (int tm = 0; tm < 4; ++tm)
#pragma unroll
        for (int tn = 0; tn < 4; ++tn)
          acc[tm][tn] = __builtin_amdgcn_mfma_f32_16x16x32_bf16(af[tm], bf[tn], acc[tm][tn], 0, 0, 0);
    }

    __builtin_amdgcn_s_barrier();        // cur reads done before re-stage
    __builtin_amdgcn_sched_barrier(0);
    cur = (cur == 2) ? 0 : cur + 1;
  }
#undef STAGE

  // ---- epilogue: direct coalesced bf16 partial store, fixed per-thread layout.
  // per (tile, ks): 256x128 = 32768 u16; chunk q (0..7) x 512 thr x 8 u16.
  u16* Pb = P + ((size_t)tile * SPLITS + ks) * 32768;
#pragma unroll
  for (int q = 0; q < 8; ++q) {
    int tm = q >> 1, tn0 = (q & 1) * 2;
    u16 r[8];
#pragma unroll
    for (int z = 0; z < 4; ++z) r[z] = f2b(acc[tm][tn0][z]);
#pragma unroll
    for (int z = 0; z < 4; ++z) r[4 + z] = f2b(acc[tm][tn0 + 1][z]);
    *(short8*)(Pb + q * 4096 + t * 8) = *(short8*)r;
  }
}

// ---- reduce 16 bf16 partial tiles + bias -> fp32 out (decodes C-layout)
__global__ __launch_bounds__(256) void reduce_kernel(const u16* __restrict__ P,
                                                     const float* __restrict__ bias_part,
                                                     float* __restrict__ out) {
  int rid = blockIdx.x * 256 + threadIdx.x;  // 65536 = tile*4096 + q*512 + t
  int tile = rid >> 12;                      // 0..15
  int rem = rid & 4095;
  int q = rem >> 9, t = rem & 511;
  const u16* base = P + (size_t)tile * SPLITS * 32768 + q * 4096 + t * 8;

  float s[8] = {0, 0, 0, 0, 0, 0, 0, 0};
#pragma unroll
  for (int ks = 0; ks < SPLITS; ++ks) {
    short8 v = *(const short8*)(base + (size_t)ks * 32768);
#pragma unroll
    for (int j = 0; j < 8; ++j) s[j] += b2f((u32)(u16)v[j]);
  }

  int w = t >> 6, l = t & 63;
  int wm = w & 3, wn = w >> 2;
  int bm = tile >> 2, bn = tile & 3;
  int row0 = bm * 256 + wm * 64 + ((l >> 4) << 2);
  int col0 = bn * 128 + wn * 64 + (l & 15);
  int tm = q >> 1, tn0 = (q & 1) * 2;
#pragma unroll
  for (int j = 0; j < 8; ++j) {
    int tn = tn0 + (j >> 2), rr = j & 3;
    int row = row0 + tm * 16 + rr;
    int col = col0 + tn * 16;
    float bsv = bias_part[2 * col] + bias_part[2 * col + 1];
    out[(size_t)row * OUT_F + col] = s[j] + bsv;
  }
}

extern "C" void kernel_launch(void* const* d_in, const int* in_sizes, int n_in,
                              void* d_out, int out_size, void* d_ws, size_t ws_size,
                              hipStream_t stream) {
  const float* x  = (const float*)d_in[0];
  const float* bw = (const float*)d_in[1];
  const float* sw = (const float*)d_in[2];
  const float* sc = (const float*)d_in[3];
  // d_in[4] = grid: uniform h=1/16 extended knots, constants baked in.
  const void* mask = d_in[5];

  const size_t B_BYTES = (size_t)OUT_F * K_TOT * 2;         // 19,922,944
  const size_t BIAS_OFF = B_BYTES;                          // 1024 floats
  const size_t A_OFF = B_BYTES + 8192;
  const size_t A_BYTES = (size_t)BATCH * K_TOT * 2;         // 39,845,888
  const size_t P_OFF = A_OFF + A_BYTES;                     // P: 16,777,216

  char* wsb = (char*)d_ws;
  u16* Bpack = (u16*)wsb;
  float* bias_part = (float*)(wsb + BIAS_OFF);
  u16* Adense = (u16*)(wsb + A_OFF);
  u16* P = (u16*)(wsb + P_OFF);

  prep_kernel<<<3072, 256, 0, stream>>>(bw, sw, sc, mask, x, Bpack, bias_part, Adense);
  gemm_fused<<<256, 512, 0, stream>>>(Adense, Bpack, P);
  reduce_kernel<<<256, 256, 0, stream>>>(P, bias_part, (float*)d_out);
}

// Round 11
// 134.915 us; speedup vs baseline: 1.0167x; 1.0167x over previous
//
#include <hip/hip_runtime.h>
#include <hip/hip_bf16.h>

// SegmentDeactivation: KAN layer folded into one bf16 GEMM.
// K = 512*36 (dense-ified 4-sparse cubic B-spline bases) + 512 (silu(x)·W_base)
//   + 512 (x·masked-slope) = 19456. bias = sum of masked intercepts.
// R21: fine phase-split port of the 8-phase template onto R18's proven
//      geometry (256x128, BK=64, 512thr, 8 waves 4Mx2N, SPLITS=16, grid 256).
//      LDS = ring of 4 HALF-K-tiles (32 cols, 24KB each, 96KB total = R18).
//      38 phases (= 2*NIT halves); per phase:
//        { 8x ds_read_b128 (slot m) ; STAGE half m+3 (3 gload_lds w16) ;
//          vmcnt(6) [confirms half m+1; NEVER 0 in-loop] ; s_barrier ;
//          setprio(1) ; 16 MFMA ; setprio(0) ; s_barrier }
//      -> loads stay 1.5 K-tiles in flight (deeper than R18, no R20-style
//      dynamic-buffer codegen trap: slot = m&3, reads are C-level).
//      Race audit: (1) phase-m reads of slot m&3 confirmed by phase m-1's
//      vmcnt + published by its barriers; (2) STAGE at phase m writes slot
//      (m-1)&3, whose readers drained before phase m-1's end barrier;
//      (3) MFMA<-ds_read dependency is compiler-tracked (C-level reads).
//      Identical MFMA accumulation order as R18 -> bit-identical numerics.
//      prep / reduce / launcher byte-identical to R18.

typedef unsigned short u16;
typedef unsigned int u32;
typedef unsigned long long u64;
typedef __attribute__((ext_vector_type(8))) short short8;
typedef __attribute__((ext_vector_type(4))) float floatx4;

#define IN_F 512
#define OUT_F 512
#define BATCH 1024
#define K_SPLINE (IN_F * 36)            // 18432
#define K_BASE_OFF K_SPLINE
#define K_LIN_OFF (K_SPLINE + IN_F)
#define K_TOT (K_SPLINE + 2 * IN_F)     // 19456
#define SPLITS 16                       // uniform: 16 x 1216 (= 38 halves of 32)
#define KPS 1216
#define NHALF 38
#define MN (BATCH * OUT_F)

static __device__ inline u16 f2b(float f) {
  union { float f; u32 u; } v; v.f = f;
  u32 r = v.u + 0x7FFFu + ((v.u >> 16) & 1u);  // round-nearest-even
  return (u16)(r >> 16);
}
static __device__ inline float b2f(u32 lo16) {  // bf16 bits (low 16) -> float
  union { u32 u; float f; } v; v.u = lo16 << 16; return v.f;
}

// ---- prep (fused): blocks 0..1023 = pack_b (one o-half each, per-block mask
//      detect, bias block-reduce); blocks 1024..3071 = dense-A build
//      (bix = blk-1024 = b*2 + half; thread t owns (b, i = i0+t)).
__global__ __launch_bounds__(256) void prep_kernel(
    const float* __restrict__ bw, const float* __restrict__ sw,
    const float* __restrict__ sc, const void* __restrict__ maskp,
    const float* __restrict__ x, u16* __restrict__ B,
    float* __restrict__ bias_part, u16* __restrict__ A) {
  __shared__ __align__(16) u64 lds64[1120 * 4];  // 35840B
  __shared__ int sflag;
  __shared__ float ws4[4];
  int blk = blockIdx.x, t = threadIdx.x;

  if (blk >= 1024) {
    // ---- dense A build
    int bix = blk - 1024;
    int b = bix >> 1;
    int i0 = (bix & 1) << 8;
    int i = i0 + t;
    float xv = x[(size_t)b * IN_F + i];

    // zero own 36-col row (72B = 9 u64), no barrier needed before scatter
    u64* myrow = lds64 + t * 9;
#pragma unroll
    for (int j = 0; j < 9; ++j) myrow[j] = 0;

    int mc = (int)floorf((xv + 1.1875f) * 16.0f);
    float gm = (float)mc * 0.0625f - 1.1875f;
    if (xv < gm) { mc -= 1; gm -= 0.0625f; }
    else if (xv >= gm + 0.0625f) { mc += 1; gm += 0.0625f; }
    if (mc >= 0 && mc <= 37) {
      float t_ = (xv - gm) * 16.0f;
      float t2 = t_ * t_, t3 = t2 * t_;
      float omt = 1.0f - t_;
      u16 r0 = f2b(omt * omt * omt * (1.0f / 6.0f));
      u16 r1 = f2b((3.0f * t3 - 6.0f * t2 + 4.0f) * (1.0f / 6.0f));
      u16 r2 = f2b((-3.0f * t3 + 3.0f * t2 + 3.0f * t_ + 1.0f) * (1.0f / 6.0f));
      float f0 = b2f(r0), f1 = b2f(r1), f2 = b2f(r2);
      u16 bv[4] = {r0, r1, r2, f2b(1.0f - f0 - f1 - f2)};
      u16* lds_u = (u16*)lds64;
#pragma unroll
      for (int j = 0; j < 4; ++j) {
        int c = mc - 3 + j;
        if ((u32)c < 35u) lds_u[t * 36 + c] = bv[j];
      }
    }
    __syncthreads();

    // coalesced dump: 256 rows x 36 u16 = 2304 u64
    u64* dstA = (u64*)(A + (size_t)b * K_TOT + (size_t)i0 * 36);
#pragma unroll
    for (int j = 0; j < 9; ++j) dstA[j * 256 + t] = lds64[j * 256 + t];

    // base / linear columns of A
    float sl = xv / (1.0f + __expf(-xv));
    A[(size_t)b * K_TOT + K_BASE_OFF + i] = f2b(sl);
    A[(size_t)b * K_TOT + K_LIN_OFF + i] = f2b(xv);
    return;
  }

  // ---- pack_b: id = o*512+i, o = blk>>1
  float* lds_f = (float*)lds64;
  int id = blk * 256 + t;
  int o = id >> 9, i = id & 511;
  int i0 = (blk & 1) * 256;

  // stage 35*256 floats = 2240 float4, vectorized (G13)
  const float* swb = sw + ((size_t)o * 512 + i0) * 35;
  const floatx4* sw4 = (const floatx4*)swb;
  floatx4* lds4 = (floatx4*)lds_f;
#pragma unroll
  for (int j = 0; j < 8; ++j) lds4[j * 256 + t] = sw4[j * 256 + t];
  if (t < 192) lds4[8 * 256 + t] = sw4[8 * 256 + t];

  // per-block mask dtype detect over THIS block's entries only.
  const u32* mw = (const u32*)maskp;
  if (t == 0) sflag = 0;
  __syncthreads();
  if (t < 64) {
    u32 w2 = mw[blk * 64 + t];   // uint8 window: bytes [blk*256,+256)
    if ((w2 & 0xFFFFFF00u) && w2 != 0x3F800000u) atomicOr(&sflag, 1);
  }
  __syncthreads();
  int fl = sflag;
  if (!(fl & 1)) {
    u32 w1 = mw[blk * 256 + t];  // int32/f32 window: words [blk*256,+256)
    if (w1 == 0x3F800000u) atomicOr(&sflag, 2);
  }
  __syncthreads();
  fl = sflag;
  bool mk;
  if (fl & 1)      mk = ((const unsigned char*)maskp)[id] != 0;
  else if (fl & 2) mk = ((const float*)maskp)[id] != 0.0f;
  else             mk = ((const int*)maskp)[id] != 0;

  float s = sc[id];
  float w[35];
#pragma unroll
  for (int c = 0; c < 35; ++c) w[c] = lds_f[t * 35 + c] * s;
  __syncthreads();

  // linear fallback params from endpoint spline values (dx = 2 exactly)
  float ys = (w[0] + 4.0f * w[1] + w[2]) * (1.0f / 6.0f);
  float ye = (w[32] + 4.0f * w[33] + w[34]) * (1.0f / 6.0f);
  float a = (ye - ys) * 0.5f;
  float bl = ys + a;

  // build out-row in regs (static indexing), store as 9 u64
  union { u16 r16[36]; u64 r64[9]; } ur;
#pragma unroll
  for (int c = 0; c < 35; ++c) ur.r16[c] = f2b(mk ? 0.0f : w[c]);
  ur.r16[35] = 0;
  u64* myrow = lds64 + t * 9;
#pragma unroll
  for (int j = 0; j < 9; ++j) myrow[j] = ur.r64[j];

  B[(size_t)o * K_TOT + K_BASE_OFF + i] = f2b(bw[id]);
  B[(size_t)o * K_TOT + K_LIN_OFF + i] = f2b(mk ? a : 0.0f);

  // bias block-reduce: sum of (mk ? bl : 0) over this block's 256 i's
  float v = mk ? bl : 0.0f;
#pragma unroll
  for (int off = 32; off >= 1; off >>= 1) v += __shfl_down(v, off);
  if ((t & 63) == 0) ws4[t >> 6] = v;
  __syncthreads();
  if (t == 0) bias_part[blk] = ws4[0] + ws4[1] + ws4[2] + ws4[3];

  u64* dst = (u64*)(B + (size_t)o * K_TOT + (size_t)i0 * 36);
#pragma unroll
  for (int j = 0; j < 9; ++j) dst[j * 256 + t] = lds64[j * 256 + t];
}

// ---- phase-split pipelined GEMM: 256x128 tile, BK=64 as 2x32-col halves,
// 512 thr (8 waves 4Mx2N, wave = 64x64, acc 4x4). Grid 256 = 1 blk/CU.
// LDS ring of 4 half-slots (A 16KB + B 8KB each = 96KB). 38 phases.
__global__ __launch_bounds__(512, 2) void gemm_fused(const u16* __restrict__ A,
                                                     const u16* __restrict__ Bp,
                                                     u16* __restrict__ P) {
  // slot layout: [0,8192) = A half (256 rows x 32 cols), [8192,12288) = B half
  __shared__ u16 ring[4][12288];   // 96 KB

  int t = threadIdx.x;
  int p = blockIdx.x;
  int tile = p & 15, ks = p >> 4;        // 16 tiles x 16 splits
  int bm = tile >> 2, bn = tile & 3;

  int w = t >> 6, l = t & 63;
  int wm = w & 3, wn = w >> 2;           // 4 M-waves x 2 N-waves

  floatx4 acc[4][4];
#pragma unroll
  for (int pp = 0; pp < 4; ++pp)
#pragma unroll
    for (int q = 0; q < 4; ++q) acc[pp][q] = (floatx4)0.0f;

  int k0s = ks * KPS;

  // staging: thread t covers (row ra2 = t>>2 in each 128-row group, chunk t&3
  // of the 4x8-u16 chunks in a 32-col half); global chunk pre-swizzled with
  // the 2-bit XOR so linear LDS dest == swizzled layout.
  int ra2 = t >> 2;                      // 0..127
  int cg2 = (t & 3) ^ (ra2 & 3);
  const u16* Ag2 = A + (size_t)(bm * 256 + ra2) * K_TOT + k0s + cg2 * 8;
  const u16* Bg2 = Bp + (size_t)(bn * 128 + ra2) * K_TOT + k0s + cg2 * 8;

  int mr = l & 15;
  int cq = l >> 4;                       // chunk 0..3 within a half

  // one half-stage = 3 gload_lds w16: A rows 0-127, A rows 128-255, B rows 0-127
#define STAGEH(slot, koff)                                                     \
  do {                                                                         \
    const u16* a_ = Ag2 + (koff);                                              \
    const u16* b_ = Bg2 + (koff);                                              \
    u16* s_ = &ring[slot][0];                                                  \
    __builtin_amdgcn_global_load_lds(                                          \
        (const __attribute__((address_space(1))) void*)a_,                     \
        (__attribute__((address_space(3))) void*)(s_ + t * 8), 16, 0, 0);      \
    __builtin_amdgcn_global_load_lds(                                          \
        (const __attribute__((address_space(1))) void*)(a_ + (size_t)128 * K_TOT),  \
        (__attribute__((address_space(3))) void*)(s_ + 4096 + t * 8), 16, 0, 0);    \
    __builtin_amdgcn_global_load_lds(                                          \
        (const __attribute__((address_space(1))) void*)b_,                     \
        (__attribute__((address_space(3))) void*)(s_ + 8192 + t * 8), 16, 0, 0);    \
  } while (0)

  // prologue: halves 0,1,2 in flight; confirm half 0 (9 outstanding -> 6)
  STAGEH(0, 0);
  STAGEH(1, 32);
  STAGEH(2, 64);
  asm volatile("s_waitcnt vmcnt(6)" ::: "memory");
  __builtin_amdgcn_s_barrier();
  __builtin_amdgcn_sched_barrier(0);

  for (int m = 0; m < NHALF; ++m) {
    int slot = m & 3;
    const u16* Acs = &ring[slot][0];
    const u16* Bcs = &ring[slot][8192];

    // phase reads (issued early; cannot cross the vmcnt asm below)
    short8 af[4], bf[4];
#pragma unroll
    for (int tm = 0; tm < 4; ++tm) {
      int row = wm * 64 + tm * 16 + mr;
      af[tm] = *(const short8*)&Acs[row * 32 + ((cq ^ (row & 3)) << 3)];
    }
#pragma unroll
    for (int tn = 0; tn < 4; ++tn) {
      int row = wn * 64 + tn * 16 + mr;
      bf[tn] = *(const short8*)&Bcs[row * 32 + ((cq ^ (row & 3)) << 3)];
    }

    // stage half m+3 and confirm half m+1 for the next phase (never drain 0
    // in steady state; tail peels 3 -> 0)
    if (m < NHALF - 3) {
      STAGEH((m + 3) & 3, (m + 3) * 32);
      asm volatile("s_waitcnt vmcnt(6)" ::: "memory");
    } else if (m == NHALF - 3) {
      asm volatile("s_waitcnt vmcnt(3)" ::: "memory");
    } else if (m == NHALF - 2) {
      asm volatile("s_waitcnt vmcnt(0)" ::: "memory");
    }
    __builtin_amdgcn_s_barrier();
    __builtin_amdgcn_sched_barrier(0);

    __builtin_amdgcn_s_setprio(1);
#pragma unroll
    for (int tm = 0; tm < 4; ++tm)
#pragma unroll
      for (int tn = 0; tn < 4; ++tn)
        acc[tm][tn] = __builtin_amdgcn_mfma_f32_16x16x32_bf16(af[tm], bf[tn], acc[tm][tn], 0, 0, 0);
    __builtin_amdgcn_s_setprio(0);

    __builtin_amdgcn_s_barrier();        // readers drained before slot reuse
    __builtin_amdgcn_sched_barrier(0);
  }
#undef STAGEH

  // ---- epilogue: direct coalesced bf16 partial store, fixed per-thread layout.
  // per (tile, ks): 256x128 = 32768 u16; chunk q (0..7) x 512 thr x 8 u16.
  u16* Pb = P + ((size_t)tile * SPLITS + ks) * 32768;
#pragma unroll
  for (int q = 0; q < 8; ++q) {
    int tm = q >> 1, tn0 = (q & 1) * 2;
    u16 r[8];
#pragma unroll
    for (int z = 0; z < 4; ++z) r[z] = f2b(acc[tm][tn0][z]);
#pragma unroll
    for (int z = 0; z < 4; ++z) r[4 + z] = f2b(acc[tm][tn0 + 1][z]);
    *(short8*)(Pb + q * 4096 + t * 8) = *(short8*)r;
  }
}

// ---- reduce 16 bf16 partial tiles + bias -> fp32 out (decodes C-layout)
__global__ __launch_bounds__(256) void reduce_kernel(const u16* __restrict__ P,
                                                     const float* __restrict__ bias_part,
                                                     float* __restrict__ out) {
  int rid = blockIdx.x * 256 + threadIdx.x;  // 65536 = tile*4096 + q*512 + t
  int tile = rid >> 12;                      // 0..15
  int rem = rid & 4095;
  int q = rem >> 9, t = rem & 511;
  const u16* base = P + (size_t)tile * SPLITS * 32768 + q * 4096 + t * 8;

  float s[8] = {0, 0, 0, 0, 0, 0, 0, 0};
#pragma unroll
  for (int ks = 0; ks < SPLITS; ++ks) {
    short8 v = *(const short8*)(base + (size_t)ks * 32768);
#pragma unroll
    for (int j = 0; j < 8; ++j) s[j] += b2f((u32)(u16)v[j]);
  }

  int w = t >> 6, l = t & 63;
  int wm = w & 3, wn = w >> 2;
  int bm = tile >> 2, bn = tile & 3;
  int row0 = bm * 256 + wm * 64 + ((l >> 4) << 2);
  int col0 = bn * 128 + wn * 64 + (l & 15);
  int tm = q >> 1, tn0 = (q & 1) * 2;
#pragma unroll
  for (int j = 0; j < 8; ++j) {
    int tn = tn0 + (j >> 2), rr = j & 3;
    int row = row0 + tm * 16 + rr;
    int col = col0 + tn * 16;
    float bsv = bias_part[2 * col] + bias_part[2 * col + 1];
    out[(size_t)row * OUT_F + col] = s[j] + bsv;
  }
}

extern "C" void kernel_launch(void* const* d_in, const int* in_sizes, int n_in,
                              void* d_out, int out_size, void* d_ws, size_t ws_size,
                              hipStream_t stream) {
  const float* x  = (const float*)d_in[0];
  const float* bw = (const float*)d_in[1];
  const float* sw = (const float*)d_in[2];
  const float* sc = (const float*)d_in[3];
  // d_in[4] = grid: uniform h=1/16 extended knots, constants baked in.
  const void* mask = d_in[5];

  const size_t B_BYTES = (size_t)OUT_F * K_TOT * 2;         // 19,922,944
  const size_t BIAS_OFF = B_BYTES;                          // 1024 floats
  const size_t A_OFF = B_BYTES + 8192;
  const size_t A_BYTES = (size_t)BATCH * K_TOT * 2;         // 39,845,888
  const size_t P_OFF = A_OFF + A_BYTES;                     // P: 16,777,216

  char* wsb = (char*)d_ws;
  u16* Bpack = (u16*)wsb;
  float* bias_part = (float*)(wsb + BIAS_OFF);
  u16* Adense = (u16*)(wsb + A_OFF);
  u16* P = (u16*)(wsb + P_OFF);

  prep_kernel<<<3072, 256, 0, stream>>>(bw, sw, sc, mask, x, Bpack, bias_part, Adense);
  gemm_fused<<<256, 512, 0, stream>>>(Adense, Bpack, P);
  reduce_kernel<<<256, 256, 0, stream>>>(P, bias_part, (float*)d_out);
}